// Round 11
// baseline (200.612 us; speedup 1.0000x reference)
//
#include <hip/hip_runtime.h>

// Problem constants
#define B_    1024
#define C_    128
#define ELL   16
#define EQ    3
#define E_    10
#define P3    23
#define P2    5
#define NSEG  176            // padded segment row: 16 f4-aligned v-segments
#define RSTR  180            // row stride
#define SRS   (48 * RSTR)    // 8640 floats per (e,c) S-slice
#define KD    28             // folded weight depth: 23 (wmax) + 5 (w2)

// packed fp32 pair: clang emits v_pk_fma_f32 / v_pk_mul_f32 for <2 x float>
typedef float v2f __attribute__((ext_vector_type(2)));

// ws layout (bytes)
#define WS_CNT   0
#define WS_LIST  64
#define WS_S     65536       // S slices: 10*128*8640*4 = 44.2 MB (ws >= 66 MB)

// segment offsets: v-th segment holds [lin_v, Q_vv, Q_v,v+1, .., Q_v,15, pad0s]
// lengths (real) 17-v, padded to x4: {20,16,16,16,16,12,12,12,12,8,8,8,8,4,4,4}
#define SEG_OFF_INIT {0,20,36,52,68,84,96,108,120,132,140,148,156,164,168,172}

// ---------------------------------------------------------------------------
// Bucketing: bucket batch indices by element, pad each bucket to x128 by
// replicating the last real index (k_main r22 strides b by 128; padded
// slots need no load guards; cp <= B_ since (1024+127)&~127 = 1024).
__device__ void do_lists(const float* __restrict__ y, int* __restrict__ cnt_g,
                         int* __restrict__ list_g, int t) {
    __shared__ int lcnt[E_];
    if (t < E_) lcnt[t] = 0;
    __syncthreads();
    for (int r = 0; r < 4; ++r) {
        int b = t + 256 * r;
        int e = 0;
        #pragma unroll
        for (int j = 1; j < E_; ++j)
            if (y[b * E_ + j] > 0.5f) e = j;
        int slot = atomicAdd(&lcnt[e], 1);
        list_g[e * B_ + slot] = b;
    }
    __syncthreads();
    if (t < E_) {
        int c0 = lcnt[t];
        cnt_g[t] = c0;
        int last = (c0 > 0) ? list_g[t * B_ + c0 - 1] : 0;
        int cp = (c0 + 127) & ~127;
        if (cp > B_) cp = B_;
        for (int s2 = c0; s2 < cp; ++s2) list_g[t * B_ + s2] = last;
    }
}

// ---------------------------------------------------------------------------
// k_s r17 (UNCHANGED -- verified win): slot-parallel phase 2 with packed
// v_pk_fma_f32; total dropped 127.5 -> 124.2 with k_main flat.
__global__ __launch_bounds__(256, 2) void k_s(const float* __restrict__ U3,
                                              const float* __restrict__ U2,
                                              const float* __restrict__ wmax,
                                              const float* __restrict__ w2,
                                              const float* __restrict__ y,
                                              float* __restrict__ Sg,
                                              int* __restrict__ cnt_g,
                                              int* __restrict__ list_g) {
    const int t = threadIdx.x;
    if (blockIdx.x == 48) {
        if (blockIdx.y == 0 && blockIdx.z == 0) do_lists(y, cnt_g, list_g, t);
        return;
    }
    __shared__ __align__(16) float wsm[KD * 32];          //  3,584 B
    __shared__ __align__(16) float SKL[NSEG * KD];        // 19,712 B

    const int j  = blockIdx.x;
    const int e  = blockIdx.y;
    const int cq = blockIdx.z;

    // ---- phase 1a: folded weight table (23 wmax + 5 w2) for this (e, cq)
    for (int idx = t; idx < KD * 32; idx += 256) {
        int k = idx >> 5, cc = idx & 31, c = cq * 32 + cc;
        wsm[idx] = (k < 23) ? wmax[(e * P3 + k) * C_ + c]
                            : w2[(e * P2 + (k - 23)) * C_ + c];
    }

    // ---- phase 1b: symmetrized coefficient rows, straight from global U3/U2
    if (t < NSEG) {
        const int SO[16] = SEG_OFF_INIT;
        int v = 0;
        #pragma unroll
        for (int s = 1; s < 16; ++s) v += (t >= SO[s]) ? 1 : 0;
        const int l    = t - SO[v];
        const int real = 17 - v;

        float row[KD];
        #pragma unroll
        for (int d = 0; d < KD; ++d) row[d] = 0.f;

        if (l == 0) {
            #pragma unroll
            for (int q = 0; q < P2; ++q)
                row[23 + q] = U2[(size_t)j * (ELL * P2) + v * P2 + q];
        } else if (l < real) {
            int i = v + l - 1;
            const float* pa = U3 + (size_t)j * (ELL * ELL * P3) + (v * ELL + i) * P3;
            const float* pb = U3 + (size_t)j * (ELL * ELL * P3) + (i * ELL + v) * P3;
            if (i != v) {
                #pragma unroll
                for (int k = 0; k < P3; ++k) row[k] = pa[k] + pb[k];
            } else {
                #pragma unroll
                for (int k = 0; k < P3; ++k) row[k] = pa[k];
            }
        }   // else: pad slot -> stays zero

        float* dst = &SKL[t * KD];
        #pragma unroll
        for (int d4 = 0; d4 < KD / 4; ++d4)
            *(float4*)(dst + 4 * d4) = make_float4(row[4 * d4], row[4 * d4 + 1],
                                                   row[4 * d4 + 2], row[4 * d4 + 3]);
    }
    __syncthreads();

    if (t >= NSEG) return;

    // ---- phase 2: 4 slots x 8 c per thread, packed fp32
    const int sg = t % 44;          // slot group: slots sg, sg+44, sg+88, sg+132
    const int cg = t / 44;          // 0..3 -> c8 = cg*8
    const int c8 = cg * 8;

    v2f acc[4][4];                  // [s][c-pair]
    #pragma unroll
    for (int s = 0; s < 4; ++s)
        #pragma unroll
        for (int cp2 = 0; cp2 < 4; ++cp2) acc[s][cp2] = (v2f){0.f, 0.f};

    #pragma unroll
    for (int k4 = 0; k4 < KD / 4; ++k4) {
        float4 sk4[4];
        #pragma unroll
        for (int s = 0; s < 4; ++s)
            sk4[s] = *(const float4*)&SKL[(sg + 44 * s) * KD + 4 * k4];
        #pragma unroll
        for (int kk = 0; kk < 4; ++kk) {
            const int k = 4 * k4 + kk;
            float4 w0 = *(const float4*)&wsm[k * 32 + c8];
            float4 w1 = *(const float4*)&wsm[k * 32 + c8 + 4];
            v2f wp0 = {w0.x, w0.y}, wp1 = {w0.z, w0.w};
            v2f wp2 = {w1.x, w1.y}, wp3 = {w1.z, w1.w};
            #pragma unroll
            for (int s = 0; s < 4; ++s) {
                const float skv = (kk == 0) ? sk4[s].x : (kk == 1) ? sk4[s].y
                                : (kk == 2) ? sk4[s].z : sk4[s].w;
                acc[s][0] += skv * wp0;
                acc[s][1] += skv * wp1;
                acc[s][2] += skv * wp2;
                acc[s][3] += skv * wp3;
            }
        }
    }

    // ---- stores: lane-consecutive in slot -> coalesced 44-lane runs
    #pragma unroll
    for (int s = 0; s < 4; ++s) {
        const int slot = sg + 44 * s;
        #pragma unroll
        for (int cc = 0; cc < 8; ++cc) {
            const int c = cq * 32 + c8 + cc;
            Sg[(size_t)(e * C_ + c) * SRS + j * RSTR + slot] = acc[s][cc >> 1][cc & 1];
        }
    }
}

// ---------------------------------------------------------------------------
// k_main r22: TRANSPOSED MAPPING -- lane <-> batch row b, serial loop <-> xx.
// r14-r21 post-mortem: k_main pinned at 42-47us across ALL of {ILP, TLP
// in-block, TLP across blocks, -40% VALU, -27% LDS ops}; occupancy stuck
// ~32%, VALUBusy <=78%. The invariant cost is the lane<->(xx,bs) mapping's
// scaffolding: 44 ds_read_b128/wave-chunk (~63K LDS-pipe cy/CU), V3L
// staging, barriers, and the width-16 reduction.
// In this mapping every S access is WAVE-UNIFORM (same (e,c,w,xx,slot) for
// all lanes) -> scalar/broadcast loads, S enters the FMA as the scalar
// operand (1 SGPR/VALU op is legal). Consequences:
//   NO LDS, NO barriers, NO anti-LICM pin, NO reduction tail.
//   Each lane owns one b: loads its x-row (16 VGPR), serially accumulates
//   oacc = sum_xx (t2_xx + v1_xx)*xm[xx], writes out[b,c,w] directly.
//   Identical FMA count to r19 (168/output-triple); pure issue-bound.
// xm[xx] indexing is static because the xx loop is fully unrolled.
// VGPR ~50; grid (384,10) x 128 thr; bucket padded to x128 (do_lists).
__global__ __launch_bounds__(128, 4) void k_main(
    const float* __restrict__ x, const float* __restrict__ Sg,
    const float* __restrict__ U1, const float* __restrict__ w1,
    const int* __restrict__ cnt_g, const int* __restrict__ list_g,
    float* __restrict__ out) {

    const int t  = threadIdx.x;           // 0..127: b-slot within bucket
    const int bx = blockIdx.x;            // 0..383: c*3 + w
    const int w  = bx % 3, c = bx / 3;
    const int e  = blockIdx.y;
    const int cnt  = cnt_g[e];
    const int cntp = (cnt + 127) & ~127;  // matches do_lists 128-pad

    const float w1ec = w1[e * C_ + c];
    const float* sbase = Sg + (size_t)(e * C_ + c) * SRS + (size_t)w * 16 * RSTR;
    const int SO[16] = SEG_OFF_INIT;

    #pragma clang loop unroll(disable)
    for (int bb = t; bb < cntp; bb += 128) {
        const int b = list_g[e * B_ + bb];
        const float* xb = x + ((size_t)b * C_ + c) * ELL;

        float xm[16];
        #pragma unroll
        for (int i4 = 0; i4 < 4; ++i4) {
            float4 a = ((const float4*)xb)[i4];
            xm[4 * i4 + 0] = a.x; xm[4 * i4 + 1] = a.y;
            xm[4 * i4 + 2] = a.z; xm[4 * i4 + 3] = a.w;
        }

        float oacc = 0.f;
        #pragma unroll
        for (int xx = 0; xx < 16; ++xx) {
            const float* srow = sbase + xx * RSTR;   // wave-uniform address
            float t2 = 0.f;
            #pragma unroll
            for (int v = 0; v < 16; ++v) {
                const int off = SO[v];
                const int nf4 = (v == 0) ? 5 : (v < 5) ? 4 : (v < 9) ? 3
                              : (v < 13) ? 2 : 1;
                float4 u = *(const float4*)(srow + off);
                float s = u.x + u.y * xm[v];
                if (v + 1 <= 15) s += u.z * xm[v + 1];
                if (v + 2 <= 15) s += u.w * xm[v + 2];
                #pragma unroll
                for (int q = 1; q < nf4; ++q) {
                    float4 u2 = *(const float4*)(srow + off + 4 * q);
                    const int i0 = v + 4 * q - 1;
                    s += u2.x * xm[i0];
                    if (i0 + 1 <= 15) s += u2.y * xm[i0 + 1];
                    if (i0 + 2 <= 15) s += u2.z * xm[i0 + 2];
                    if (i0 + 3 <= 15) s += u2.w * xm[i0 + 3];
                }
                t2 += xm[v] * s;
            }
            const float v1x = U1[w * 16 + xx] * w1ec;   // uniform scalars
            oacc += (t2 + v1x) * xm[xx];
        }

        if (bb < cnt)
            out[(size_t)b * (C_ * EQ) + c * EQ + w] = oacc;
    }
}

// ---------------------------------------------------------------------------
extern "C" void kernel_launch(void* const* d_in, const int* in_sizes, int n_in,
                              void* d_out, int out_size, void* d_ws, size_t ws_size,
                              hipStream_t stream) {
    const float* x    = (const float*)d_in[0];
    const float* y    = (const float*)d_in[1];
    const float* U3   = (const float*)d_in[2];
    const float* U2   = (const float*)d_in[3];
    const float* U1   = (const float*)d_in[4];
    const float* wmax = (const float*)d_in[5];
    const float* w2   = (const float*)d_in[6];
    const float* w1   = (const float*)d_in[7];
    float* out = (float*)d_out;
    char*  ws  = (char*)d_ws;

    int*   cnt_g  = (int*)(ws + WS_CNT);
    int*   list_g = (int*)(ws + WS_LIST);
    float* Sg     = (float*)(ws + WS_S);
    (void)ws_size;   // 44.3 MB needed; harness ws confirmed >= 66 MB

    k_s<<<dim3(49, E_, 4), 256, 0, stream>>>(U3, U2, wmax, w2, y, Sg, cnt_g, list_g);
    k_main<<<dim3(C_ * EQ, E_), 128, 0, stream>>>(x, Sg, U1, w1, cnt_g, list_g, out);
}

// Round 12
// 125.237 us; speedup vs baseline: 1.6019x; 1.6019x over previous
//
#include <hip/hip_runtime.h>

// Problem constants
#define B_    1024
#define C_    128
#define ELL   16
#define EQ    3
#define E_    10
#define P3    23
#define P2    5
#define NSEG  176            // padded segment row: 16 f4-aligned v-segments
#define RSTR  180            // row stride (180%32=20 -> 8 bank-starts x2 = 2-way, free)
#define SRS   (48 * RSTR)    // 8640 floats per (e,c) S-slice
#define KD    28             // folded weight depth: 23 (wmax) + 5 (w2)

// packed fp32 pair: clang emits v_pk_fma_f32 / v_pk_mul_f32 for <2 x float>
typedef float v2f __attribute__((ext_vector_type(2)));

// ws layout (bytes)
#define WS_CNT   0
#define WS_LIST  64
#define WS_S     65536       // S slices: 10*128*8640*4 = 44.2 MB (ws >= 66 MB)

// segment offsets: v-th segment holds [lin_v, Q_vv, Q_v,v+1, .., Q_v,15, pad0s]
// lengths (real) 17-v, padded to x4: {20,16,16,16,16,12,12,12,12,8,8,8,8,4,4,4}
#define SEG_OFF_INIT {0,20,36,52,68,84,96,108,120,132,140,148,156,164,168,172}

// DPP row_ror add: lane i += lane (i+N) mod 16 within its 16-lane DPP row.
// Chained over N=1,2,4,8: width-16 sum-to-all; bit-identical tree to the
// __shfl_xor butterfly for the storing lanes. VALU pipe, zero registers.
// VERIFIED r18b/r19/r20 (passed, absmax identical).
template <int CTRL>
__device__ __forceinline__ float dpp_ror_add(float v) {
    int s = __float_as_int(v);
    int r = __builtin_amdgcn_update_dpp(s, s, CTRL, 0xF, 0xF, false);
    return v + __int_as_float(r);
}
__device__ __forceinline__ float row16_sum(float v) {
    v = dpp_ror_add<0x121>(v);   // row_ror:1
    v = dpp_ror_add<0x122>(v);   // row_ror:2
    v = dpp_ror_add<0x124>(v);   // row_ror:4
    v = dpp_ror_add<0x128>(v);   // row_ror:8
    return v;
}

// ---------------------------------------------------------------------------
// Bucketing: bucket batch indices by element, pad each bucket to x64 by
// replicating the last real index (k_main needs no load guards). Exact r19.
__device__ void do_lists(const float* __restrict__ y, int* __restrict__ cnt_g,
                         int* __restrict__ list_g, int t) {
    __shared__ int lcnt[E_];
    if (t < E_) lcnt[t] = 0;
    __syncthreads();
    for (int r = 0; r < 4; ++r) {
        int b = t + 256 * r;
        int e = 0;
        #pragma unroll
        for (int j = 1; j < E_; ++j)
            if (y[b * E_ + j] > 0.5f) e = j;
        int slot = atomicAdd(&lcnt[e], 1);
        list_g[e * B_ + slot] = b;
    }
    __syncthreads();
    if (t < E_) {
        int c0 = lcnt[t];
        cnt_g[t] = c0;
        int last = (c0 > 0) ? list_g[t * B_ + c0 - 1] : 0;
        int cp = (c0 + 63) & ~63;
        if (cp > B_) cp = B_;
        for (int s2 = c0; s2 < cp; ++s2) list_g[t * B_ + s2] = last;
    }
}

// ---------------------------------------------------------------------------
// k_s r17 (UNCHANGED -- verified win): slot-parallel phase 2 with packed
// v_pk_fma_f32; total dropped 127.5 -> 124.2 with k_main flat.
__global__ __launch_bounds__(256, 2) void k_s(const float* __restrict__ U3,
                                              const float* __restrict__ U2,
                                              const float* __restrict__ wmax,
                                              const float* __restrict__ w2,
                                              const float* __restrict__ y,
                                              float* __restrict__ Sg,
                                              int* __restrict__ cnt_g,
                                              int* __restrict__ list_g) {
    const int t = threadIdx.x;
    if (blockIdx.x == 48) {
        if (blockIdx.y == 0 && blockIdx.z == 0) do_lists(y, cnt_g, list_g, t);
        return;
    }
    __shared__ __align__(16) float wsm[KD * 32];          //  3,584 B
    __shared__ __align__(16) float SKL[NSEG * KD];        // 19,712 B

    const int j  = blockIdx.x;
    const int e  = blockIdx.y;
    const int cq = blockIdx.z;

    // ---- phase 1a: folded weight table (23 wmax + 5 w2) for this (e, cq)
    for (int idx = t; idx < KD * 32; idx += 256) {
        int k = idx >> 5, cc = idx & 31, c = cq * 32 + cc;
        wsm[idx] = (k < 23) ? wmax[(e * P3 + k) * C_ + c]
                            : w2[(e * P2 + (k - 23)) * C_ + c];
    }

    // ---- phase 1b: symmetrized coefficient rows, straight from global U3/U2
    if (t < NSEG) {
        const int SO[16] = SEG_OFF_INIT;
        int v = 0;
        #pragma unroll
        for (int s = 1; s < 16; ++s) v += (t >= SO[s]) ? 1 : 0;
        const int l    = t - SO[v];
        const int real = 17 - v;

        float row[KD];
        #pragma unroll
        for (int d = 0; d < KD; ++d) row[d] = 0.f;

        if (l == 0) {
            #pragma unroll
            for (int q = 0; q < P2; ++q)
                row[23 + q] = U2[(size_t)j * (ELL * P2) + v * P2 + q];
        } else if (l < real) {
            int i = v + l - 1;
            const float* pa = U3 + (size_t)j * (ELL * ELL * P3) + (v * ELL + i) * P3;
            const float* pb = U3 + (size_t)j * (ELL * ELL * P3) + (i * ELL + v) * P3;
            if (i != v) {
                #pragma unroll
                for (int k = 0; k < P3; ++k) row[k] = pa[k] + pb[k];
            } else {
                #pragma unroll
                for (int k = 0; k < P3; ++k) row[k] = pa[k];
            }
        }   // else: pad slot -> stays zero

        float* dst = &SKL[t * KD];
        #pragma unroll
        for (int d4 = 0; d4 < KD / 4; ++d4)
            *(float4*)(dst + 4 * d4) = make_float4(row[4 * d4], row[4 * d4 + 1],
                                                   row[4 * d4 + 2], row[4 * d4 + 3]);
    }
    __syncthreads();

    if (t >= NSEG) return;

    // ---- phase 2: 4 slots x 8 c per thread, packed fp32
    const int sg = t % 44;          // slot group: slots sg, sg+44, sg+88, sg+132
    const int cg = t / 44;          // 0..3 -> c8 = cg*8
    const int c8 = cg * 8;

    v2f acc[4][4];                  // [s][c-pair]
    #pragma unroll
    for (int s = 0; s < 4; ++s)
        #pragma unroll
        for (int cp2 = 0; cp2 < 4; ++cp2) acc[s][cp2] = (v2f){0.f, 0.f};

    #pragma unroll
    for (int k4 = 0; k4 < KD / 4; ++k4) {
        float4 sk4[4];
        #pragma unroll
        for (int s = 0; s < 4; ++s)
            sk4[s] = *(const float4*)&SKL[(sg + 44 * s) * KD + 4 * k4];
        #pragma unroll
        for (int kk = 0; kk < 4; ++kk) {
            const int k = 4 * k4 + kk;
            float4 w0 = *(const float4*)&wsm[k * 32 + c8];
            float4 w1 = *(const float4*)&wsm[k * 32 + c8 + 4];
            v2f wp0 = {w0.x, w0.y}, wp1 = {w0.z, w0.w};
            v2f wp2 = {w1.x, w1.y}, wp3 = {w1.z, w1.w};
            #pragma unroll
            for (int s = 0; s < 4; ++s) {
                const float skv = (kk == 0) ? sk4[s].x : (kk == 1) ? sk4[s].y
                                : (kk == 2) ? sk4[s].z : sk4[s].w;
                acc[s][0] += skv * wp0;
                acc[s][1] += skv * wp1;
                acc[s][2] += skv * wp2;
                acc[s][3] += skv * wp3;
            }
        }
    }

    // ---- stores: lane-consecutive in slot -> coalesced 44-lane runs
    #pragma unroll
    for (int s = 0; s < 4; ++s) {
        const int slot = sg + 44 * s;
        #pragma unroll
        for (int cc = 0; cc < 8; ++cc) {
            const int c = cq * 32 + c8 + cc;
            Sg[(size_t)(e * C_ + c) * SRS + j * RSTR + slot] = acc[s][cc >> 1][cc & 1];
        }
    }
}

// ---------------------------------------------------------------------------
// k_main r23 = EXACT r19 body (best: 42.4us) with ONE change:
// __launch_bounds__(256, 2) -> (256, 4).
// r22 post-mortem: transposed/scalar mapping 119us (serial s_load chains,
// 2-wave blocks) -- reverted. The unexplained invariant across r14-r22:
// residency stuck at ~2.6 blocks/CU (occ 33%) though reported VGPR=64 +
// LDS 11.8KB should allow 8 blocks/CU. 2.6 blocks = 512/192 waves/SIMD --
// matches a REAL allocation of ~192 VGPR (reported 64 is the granule
// artifact; r13/r18b already showed reporting != reality). If occupancy,
// not any pipe, is the binding constraint, it explains ALL flat results.
// (256,4) forces the allocator under 128 VGPR. Live-value audit of this
// body: xm 64 + inner/t2 8 + bidx/xo 8 + u 4 + addr ~15 ~= 100 -> fits.
// Tripwire: WRITE_SIZE >> 12.3MB = spill -> revert to (256,2).
// CRITICAL (unchanged): __syncthreads() pin + unroll(disable) -- LICM
// hoisting LDS reads caused the r5/r6 VGPR blowup/spill.
__global__ __launch_bounds__(256, 4) void k_main(
    const float* __restrict__ x, const float* __restrict__ Sg,
    const float* __restrict__ U1, const float* __restrict__ w1,
    const int* __restrict__ cnt_g, const int* __restrict__ list_g,
    float* __restrict__ out) {

    __shared__ __align__(16) float V3L[16 * RSTR];   // 11,520 B

    const int t  = threadIdx.x;
    const int bx = blockIdx.x;
    const int w  = bx % 3, c = bx / 3;
    const int e  = blockIdx.y;
    const int xx = t & 15, bs = t >> 4;
    const int cnt  = cnt_g[e];
    const int cntp = (cnt + 63) & ~63;

    // ---- fill V3L: this w's 16 rows = 2880 floats = 720 f4, straight copy
    {
        const float4* src = (const float4*)(Sg + (size_t)(e * C_ + c) * SRS
                                            + (size_t)w * 16 * RSTR);
        float4* dst = (float4*)V3L;
        #pragma unroll
        for (int r = 0; r < 2; ++r) dst[t + 256 * r] = src[t + 256 * r];
        if (t < 208) dst[512 + t] = src[512 + t];
    }
    const float v1x = U1[w * 16 + xx] * w1[e * C_ + c];
    __syncthreads();

    const float* v3p = &V3L[xx * RSTR];
    const int SO[16] = SEG_OFF_INIT;

    // ---- chunk loop: 64 rows per chunk, 4 per thread ----
    #pragma clang loop unroll(disable)
    for (int base = 0; base < cntp; base += 64) {
        __syncthreads();   // anti-LICM liveness pin (see header note)

        const int slot = base + bs * 4;
        int bidx[4];
        #pragma unroll
        for (int r = 0; r < 4; ++r) bidx[r] = list_g[e * B_ + slot + r];

        float xm[4][16];
        float xo[4];
        #pragma unroll
        for (int r = 0; r < 4; ++r) {
            const float* xb = x + ((size_t)bidx[r] * C_ + c) * ELL;
            #pragma unroll
            for (int i4 = 0; i4 < 4; ++i4) {
                float4 a = ((const float4*)xb)[i4];
                xm[r][4 * i4 + 0] = a.x; xm[r][4 * i4 + 1] = a.y;
                xm[r][4 * i4 + 2] = a.z; xm[r][4 * i4 + 3] = a.w;
            }
            xo[r] = xb[xx];   // own-x element (L1 hit; no dynamic reg index)
        }

        float t2[4] = {0.f, 0.f, 0.f, 0.f};
        #pragma unroll
        for (int v = 0; v < 16; ++v) {
            const int off = SO[v];
            const int nf4 = (v == 0) ? 5 : (v < 5) ? 4 : (v < 9) ? 3 : (v < 13) ? 2 : 1;
            float inner[4];
            {   // first f4: [lin, Q_vv, Q_v,v+1, Q_v,v+2]
                float4 u = *(const float4*)(v3p + off);
                #pragma unroll
                for (int r = 0; r < 4; ++r) {
                    float s = u.x + u.y * xm[r][v];
                    if (v + 1 <= 15) s += u.z * xm[r][v + 1];
                    if (v + 2 <= 15) s += u.w * xm[r][v + 2];
                    inner[r] = s;
                }
            }
            #pragma unroll
            for (int q = 1; q < nf4; ++q) {
                float4 u = *(const float4*)(v3p + off + 4 * q);
                const int i0 = v + 4 * q - 1;
                #pragma unroll
                for (int r = 0; r < 4; ++r) {
                    inner[r] += u.x * xm[r][i0];
                    if (i0 + 1 <= 15) inner[r] += u.y * xm[r][i0 + 1];
                    if (i0 + 2 <= 15) inner[r] += u.z * xm[r][i0 + 2];
                    if (i0 + 3 <= 15) inner[r] += u.w * xm[r][i0 + 3];
                }
            }
            #pragma unroll
            for (int r = 0; r < 4; ++r) t2[r] += xm[r][v] * inner[r];
        }

        // out[b,c,w] = sum_xx (t2 + v1[xx]) * x[xx]  -- DPP row-16 reduction
        float cv[4];
        #pragma unroll
        for (int r = 0; r < 4; ++r) cv[r] = (t2[r] + v1x) * xo[r];
        #pragma unroll
        for (int r = 0; r < 4; ++r) cv[r] = row16_sum(cv[r]);
        if (xx == 0) {
            #pragma unroll
            for (int r = 0; r < 4; ++r)
                if (slot + r < cnt)
                    out[(size_t)bidx[r] * (C_ * EQ) + c * EQ + w] = cv[r];
        }
    }
}

// ---------------------------------------------------------------------------
extern "C" void kernel_launch(void* const* d_in, const int* in_sizes, int n_in,
                              void* d_out, int out_size, void* d_ws, size_t ws_size,
                              hipStream_t stream) {
    const float* x    = (const float*)d_in[0];
    const float* y    = (const float*)d_in[1];
    const float* U3   = (const float*)d_in[2];
    const float* U2   = (const float*)d_in[3];
    const float* U1   = (const float*)d_in[4];
    const float* wmax = (const float*)d_in[5];
    const float* w2   = (const float*)d_in[6];
    const float* w1   = (const float*)d_in[7];
    float* out = (float*)d_out;
    char*  ws  = (char*)d_ws;

    int*   cnt_g  = (int*)(ws + WS_CNT);
    int*   list_g = (int*)(ws + WS_LIST);
    float* Sg     = (float*)(ws + WS_S);
    (void)ws_size;   // 44.3 MB needed; harness ws confirmed >= 66 MB

    k_s<<<dim3(49, E_, 4), 256, 0, stream>>>(U3, U2, wmax, w2, y, Sg, cnt_g, list_g);
    k_main<<<dim3(C_ * EQ, E_), 256, 0, stream>>>(x, Sg, U1, w1, cnt_g, list_g, out);
}